// Round 15
// baseline (182.009 us; speedup 1.0000x reference)
//
#include <hip/hip_runtime.h>
#include <math.h>

#define S_LEN 2048
#define E_DIM 512
#define NE (S_LEN * E_DIM)
#define H_NUM 8
#define WH 32
#define NOFF 65
#define PROW (H_NUM * NOFF) /* 520 */
#define PN (S_LEN * PROW)

typedef float f32x4 __attribute__((ext_vector_type(4)));
typedef short short8 __attribute__((ext_vector_type(8)));

__device__ __forceinline__ unsigned short f2bf(float f) {
    union { float f; unsigned u; } cv; cv.f = f;
    unsigned u = cv.u;
    u += 0x7fffu + ((u >> 16) & 1u);   // RNE
    return (unsigned short)(u >> 16);
}
__device__ __forceinline__ unsigned pk2(float x, float y) {
    return (unsigned)f2bf(x) | ((unsigned)f2bf(y) << 16);
}

// ---------------------------------------------------------------------------
// qkv (proven R3/R8) + fused Wo transpose (z==3, proven R2/R14).
// ---------------------------------------------------------------------------
__device__ __forceinline__ void mfma_gemm_f32(
    const float* __restrict__ A, const float* __restrict__ W,
    const float* __restrict__ bias, float* __restrict__ C,
    float scale, int m0, int n0)
{
    __shared__ unsigned short As[64 * 40];
    __shared__ unsigned short Bs[64 * 40];
    const int tid = threadIdx.x;
    const int lane = tid & 63, wave = tid >> 6;
    const int quad = lane >> 4, l16 = lane & 15;
    const int wr = (wave >> 1) * 32, wc = (wave & 1) * 32;
    const int ar = tid >> 2, ac = (tid & 3) * 8;
    const int bn = tid & 63, bk0 = (tid >> 6) * 8;

    f32x4 acc00 = {0.f,0.f,0.f,0.f}, acc01 = acc00, acc10 = acc00, acc11 = acc00;

    for (int kk = 0; kk < E_DIM; kk += 32) {
        float4 a0 = *(const float4*)(A + (size_t)(m0 + ar) * E_DIM + kk + ac);
        float4 a1 = *(const float4*)(A + (size_t)(m0 + ar) * E_DIM + kk + ac + 4);
        float b[8];
#pragma unroll
        for (int j = 0; j < 8; ++j)
            b[j] = W[(size_t)(kk + bk0 + j) * E_DIM + n0 + bn];
        __syncthreads();
        uint4 ap; ap.x = pk2(a0.x, a0.y); ap.y = pk2(a0.z, a0.w);
        ap.z = pk2(a1.x, a1.y); ap.w = pk2(a1.z, a1.w);
        *(uint4*)(As + ar * 40 + ac) = ap;
        uint4 bp; bp.x = pk2(b[0], b[1]); bp.y = pk2(b[2], b[3]);
        bp.z = pk2(b[4], b[5]); bp.w = pk2(b[6], b[7]);
        *(uint4*)(Bs + bn * 40 + bk0) = bp;
        __syncthreads();
        short8 fa0 = *(const short8*)(As + (wr + l16) * 40 + quad * 8);
        short8 fa1 = *(const short8*)(As + (wr + 16 + l16) * 40 + quad * 8);
        short8 fb0 = *(const short8*)(Bs + (wc + l16) * 40 + quad * 8);
        short8 fb1 = *(const short8*)(Bs + (wc + 16 + l16) * 40 + quad * 8);
        acc00 = __builtin_amdgcn_mfma_f32_16x16x32_bf16(fa0, fb0, acc00, 0, 0, 0);
        acc01 = __builtin_amdgcn_mfma_f32_16x16x32_bf16(fa0, fb1, acc01, 0, 0, 0);
        acc10 = __builtin_amdgcn_mfma_f32_16x16x32_bf16(fa1, fb0, acc10, 0, 0, 0);
        acc11 = __builtin_amdgcn_mfma_f32_16x16x32_bf16(fa1, fb1, acc11, 0, 0, 0);
    }

#pragma unroll
    for (int mi = 0; mi < 2; ++mi) {
#pragma unroll
        for (int ni = 0; ni < 2; ++ni) {
            f32x4 a = (mi == 0) ? ((ni == 0) ? acc00 : acc01)
                                : ((ni == 0) ? acc10 : acc11);
            int n = n0 + wc + ni * 16 + l16;
            float bval = bias[n];
#pragma unroll
            for (int r = 0; r < 4; ++r) {
                int m = m0 + wr + mi * 16 + quad * 4 + r;
                C[(size_t)m * E_DIM + n] = (a[r] + bval) * scale;
            }
        }
    }
}

__global__ __launch_bounds__(256)
void qkv_gemm(const float* __restrict__ x,
              const float* __restrict__ Wq, const float* __restrict__ bq,
              const float* __restrict__ Wk, const float* __restrict__ bk,
              const float* __restrict__ Wv, const float* __restrict__ bv,
              const float* __restrict__ Wo, unsigned short* __restrict__ WoT,
              float* __restrict__ q, float* __restrict__ k, float* __restrict__ v)
{
    if (blockIdx.z == 3) {
        if (blockIdx.y >= 8) return;
        __shared__ float tile[64][65];
        const int tid = threadIdx.x;
        const int n0 = blockIdx.x * 64, k0 = blockIdx.y * 64;
        const int r = tid >> 2;
#pragma unroll
        for (int s = 0; s < 4; ++s) {
            int c4 = (tid & 3) + 4 * s;
            float4 vv = ((const float4*)(Wo + (size_t)(k0 + r) * E_DIM + n0))[c4];
            tile[r][c4 * 4 + 0] = vv.x; tile[r][c4 * 4 + 1] = vv.y;
            tile[r][c4 * 4 + 2] = vv.z; tile[r][c4 * 4 + 3] = vv.w;
        }
        __syncthreads();
#pragma unroll
        for (int s = 0; s < 4; ++s) {
            int c4 = (tid & 3) + 4 * s;
            ushort4 o;
            o.x = f2bf(tile[c4 * 4 + 0][r]);
            o.y = f2bf(tile[c4 * 4 + 1][r]);
            o.z = f2bf(tile[c4 * 4 + 2][r]);
            o.w = f2bf(tile[c4 * 4 + 3][r]);
            *(ushort4*)(WoT + (size_t)(n0 + r) * E_DIM + k0 + c4 * 4) = o;
        }
        return;
    }
    const float* W; const float* b; float* o; float sc;
    if (blockIdx.z == 0)      { W = Wq; b = bq; o = q; sc = 0.125f; }
    else if (blockIdx.z == 1) { W = Wk; b = bk; o = k; sc = 1.0f; }
    else                      { W = Wv; b = bv; o = v; sc = 1.0f; }
    mfma_gemm_f32(x, W, b, o, sc, blockIdx.y * 64, blockIdx.x * 64);
}

// ---------------------------------------------------------------------------
// scores_d1 (proven R8): scores + edge-softmax + diffusion step 1, fused.
// ---------------------------------------------------------------------------
#define SDN 32
__global__ __launch_bounds__(256)
void scores_d1(const float* __restrict__ q, const float* __restrict__ k,
               const float* __restrict__ v, const float* __restrict__ amask,
               float* __restrict__ P, float* __restrict__ hA)
{
    const int i0 = blockIdx.x * SDN;
    const int h  = blockIdx.y;
    const int tid = threadIdx.x;
    __shared__ float ks[96 * 68];      // k rows [i0-32,i0+64); later v rows
    __shared__ float am[96];
    __shared__ float sc[SDN * 66];
    __shared__ float smx[SDN], sidn[SDN];
    __shared__ float ps[SDN * NOFF];

    for (int e = tid; e < 96 * 16; e += 256) {
        int lr = e >> 4, c4 = e & 15;
        int j = i0 - WH + lr;
        int jc = min(max(j, 0), S_LEN - 1);
        *(float4*)(ks + lr * 68 + c4 * 4) =
            *(const float4*)(k + (size_t)jc * E_DIM + h * 64 + c4 * 4);
    }
    if (tid < 96) {
        int j = i0 - WH + tid;
        am[tid] = (j >= 0 && j < S_LEN) ? amask[j] : -1.0f;
    }

    const int dst = tid >> 3;
    const int og  = tid & 7;
    float4 qreg[16];
    {
        const float4* qrow = (const float4*)(q + (size_t)(i0 + dst) * E_DIM + h * 64);
#pragma unroll
        for (int t = 0; t < 16; ++t) qreg[t] = qrow[t];
    }
    __syncthreads();

    for (int off = og; off < NOFF; off += 8) {
        int j = i0 + dst + off - WH;
        float s;
        if (j < 0 || j >= S_LEN) {
            s = -INFINITY;
        } else {
            int lr = dst + off;
            const float4* kr = (const float4*)(ks + lr * 68);
            float acc = 0.f;
#pragma unroll
            for (int t = 0; t < 16; ++t) {
                float4 a = qreg[t], bb = kr[t];
                acc += a.x * bb.x + a.y * bb.y + a.z * bb.z + a.w * bb.w;
            }
            s = (am[lr] >= 0.f) ? acc : -1e9f;
        }
        sc[dst * 66 + off] = s;
    }
    __syncthreads();   // sc done; ks no longer read as k

    for (int e = tid; e < 96 * 16; e += 256) {
        int lr = e >> 4, c4 = e & 15;
        int j = i0 - WH + lr;
        int jc = min(max(j, 0), S_LEN - 1);
        *(float4*)(ks + lr * 68 + c4 * 4) =
            *(const float4*)(v + (size_t)jc * E_DIM + h * 64 + c4 * 4);
    }
    if (tid < SDN) {
        float mx = -INFINITY;
        for (int o = 0; o < NOFF; ++o) mx = fmaxf(mx, sc[tid * 66 + o]);
        float dn = 0.f;
        for (int o = 0; o < NOFF; ++o) dn += expf(sc[tid * 66 + o] - mx);
        smx[tid] = mx; sidn[tid] = 1.f / dn;
    }
    __syncthreads();

    for (int e = tid; e < SDN * NOFF; e += 256) {
        int d = e / NOFF, off = e - d * NOFF;
        float pv = expf(sc[d * 66 + off] - smx[d]) * sidn[d];
        P[(size_t)(i0 + d) * PROW + h * NOFF + off] = pv;
        ps[e] = pv;
    }
    __syncthreads();

    {
        const int ci = tid & 15;
        const int ob = (tid >> 4) * 2;
        float4 a0 = {0,0,0,0}, a1 = a0;
        for (int lr = ob; lr < ob + 66; ++lr) {
            float4 hval = *(const float4*)(ks + lr * 68 + ci * 4);
            int o0 = lr - ob;
            if (o0 <= 64) {
                float p = ps[ob * NOFF + o0];
                a0.x += p * hval.x; a0.y += p * hval.y; a0.z += p * hval.z; a0.w += p * hval.w;
            }
            int o1 = o0 - 1;
            if ((unsigned)o1 <= 64u) {
                float p = ps[(ob + 1) * NOFF + o1];
                a1.x += p * hval.x; a1.y += p * hval.y; a1.z += p * hval.z; a1.w += p * hval.w;
            }
        }
#pragma unroll
        for (int r = 0; r < 2; ++r) {
            float4 a = r ? a1 : a0;
            float4 vv = *(const float4*)(ks + (WH + ob + r) * 68 + ci * 4);
            float4 o;
            o.x = 0.9f * a.x + 0.1f * vv.x;
            o.y = 0.9f * a.y + 0.1f * vv.y;
            o.z = 0.9f * a.z + 0.1f * vv.z;
            o.w = 0.9f * a.w + 0.1f * vv.w;
            *(float4*)(hA + (size_t)(i0 + ob + r) * E_DIM + h * 64 + ci * 4) = o;
        }
    }
}

// ---------------------------------------------------------------------------
// diffuse3m (proven R12/R13/R14): THREE diffusion steps via banded MFMA.
// ---------------------------------------------------------------------------
__global__ __launch_bounds__(512)
void diffuse3m(const float* __restrict__ hin, const float* __restrict__ v,
               const float* __restrict__ P, float* __restrict__ hout)
{
    __shared__ unsigned short inT[64 * 264];  // [col][in-row 0..255]; later m2T
    __shared__ unsigned short m1T[64 * 200];  // [col][mid1-row 0..191]
    __shared__ unsigned short ps[192 * 66];   // [row rk1][off 0..64] bf16
    unsigned short* m2T = inT;                // [col][mid2-row 0..127] stride 136
    const int i0 = blockIdx.x * 64;
    const int h  = blockIdx.y;
    const int c0 = h * 64;
    const int tid  = threadIdx.x;
    const int lane = tid & 63, wave = tid >> 6;
    const int quad = lane >> 4, l16 = lane & 15;

    for (int e = tid; e < 128 * 16; e += 512) {
        int rp = (e >> 4) * 2, c4 = (e & 15) * 4;
        int ja = min(max(i0 - 96 + rp,     0), S_LEN - 1);
        int jb = min(max(i0 - 96 + rp + 1, 0), S_LEN - 1);
        float4 ha = *(const float4*)(hin + (size_t)ja * E_DIM + c0 + c4);
        float4 hb = *(const float4*)(hin + (size_t)jb * E_DIM + c0 + c4);
        *(unsigned*)(inT + (c4 + 0) * 264 + rp) = pk2(ha.x, hb.x);
        *(unsigned*)(inT + (c4 + 1) * 264 + rp) = pk2(ha.y, hb.y);
        *(unsigned*)(inT + (c4 + 2) * 264 + rp) = pk2(ha.z, hb.z);
        *(unsigned*)(inT + (c4 + 3) * 264 + rp) = pk2(ha.w, hb.w);
    }
    for (int e = tid; e < 192 * 33; e += 512) {
        int mr = e / 33, t = e - mr * 33;
        int jc = min(max(i0 - 64 + mr, 0), S_LEN - 1);
        const float* pr = P + (size_t)jc * PROW + h * NOFF;
        if (t < 32)
            *(unsigned*)(ps + mr * 66 + t * 2) = pk2(pr[t * 2], pr[t * 2 + 1]);
        else
            ps[mr * 66 + 64] = f2bf(pr[64]);
    }
    __syncthreads();

    // ---- s1: mid1 rows (rk1 0..191). 24 units.
#pragma unroll
    for (int uu = 0; uu < 3; ++uu) {
        int u = wave + uu * 8;
        int mtb = (u >> 1) * 16;
        int ntb = (u & 1) * 32;
        f32x4 a0 = {0.f,0.f,0.f,0.f}, a1 = a0;
        int ks0 = mtb >> 5;
        const int m = mtb + l16;
#pragma unroll
        for (int t = 0; t < 3; ++t) {
            int k0q = (ks0 + t) * 32 + quad * 8;
            short8 fa;
#pragma unroll
            for (int j = 0; j < 8; ++j) {
                int idx = k0q + j - m;
                int idc = min(max(idx, 0), 64);
                unsigned short pv = ps[m * 66 + idc];
                fa[j] = ((unsigned)idx <= 64u) ? (short)pv : (short)0;
            }
            short8 fb0 = *(const short8*)(inT + (ntb + l16) * 264 + k0q);
            short8 fb1 = *(const short8*)(inT + (ntb + 16 + l16) * 264 + k0q);
            a0 = __builtin_amdgcn_mfma_f32_16x16x32_bf16(fa, fb0, a0, 0, 0, 0);
            a1 = __builtin_amdgcn_mfma_f32_16x16x32_bf16(fa, fb1, a1, 0, 0, 0);
        }
#pragma unroll
        for (int nt = 0; nt < 2; ++nt) {
            f32x4 a = nt ? a1 : a0;
            int n = ntb + nt * 16 + l16;
            float o[4];
#pragma unroll
            for (int r = 0; r < 4; ++r) {
                int gm = min(max(i0 - 64 + mtb + quad * 4 + r, 0), S_LEN - 1);
                o[r] = 0.9f * a[r] + 0.1f * v[(size_t)gm * E_DIM + c0 + n];
            }
            *(unsigned*)(m1T + n * 200 + mtb + quad * 4)     = pk2(o[0], o[1]);
            *(unsigned*)(m1T + n * 200 + mtb + quad * 4 + 2) = pk2(o[2], o[3]);
        }
    }
    __syncthreads();

    // ---- s2: mid2 rows (rk2 0..127), source m1T, P row rk2+32. 16 units.
#pragma unroll
    for (int uu = 0; uu < 2; ++uu) {
        int u = wave + uu * 8;
        int mtb = (u >> 1) * 16;
        int ntb = (u & 1) * 32;
        f32x4 a0 = {0.f,0.f,0.f,0.f}, a1 = a0;
        int ks0 = mtb >> 5;
        const int m = mtb + l16;
#pragma unroll
        for (int t = 0; t < 3; ++t) {
            int k0q = (ks0 + t) * 32 + quad * 8;
            short8 fa;
#pragma unroll
            for (int j = 0; j < 8; ++j) {
                int idx = k0q + j - m;
                int idc = min(max(idx, 0), 64);
                unsigned short pv = ps[(m + 32) * 66 + idc];
                fa[j] = ((unsigned)idx <= 64u) ? (short)pv : (short)0;
            }
            short8 fb0 = *(const short8*)(m1T + (ntb + l16) * 200 + k0q);
            short8 fb1 = *(const short8*)(m1T + (ntb + 16 + l16) * 200 + k0q);
            a0 = __builtin_amdgcn_mfma_f32_16x16x32_bf16(fa, fb0, a0, 0, 0, 0);
            a1 = __builtin_amdgcn_mfma_f32_16x16x32_bf16(fa, fb1, a1, 0, 0, 0);
        }
#pragma unroll
        for (int nt = 0; nt < 2; ++nt) {
            f32x4 a = nt ? a1 : a0;
            int n = ntb + nt * 16 + l16;
            float o[4];
#pragma unroll
            for (int r = 0; r < 4; ++r) {
                int gm = min(max(i0 - 32 + mtb + quad * 4 + r, 0), S_LEN - 1);
                o[r] = 0.9f * a[r] + 0.1f * v[(size_t)gm * E_DIM + c0 + n];
            }
            *(unsigned*)(m2T + n * 136 + mtb + quad * 4)     = pk2(o[0], o[1]);
            *(unsigned*)(m2T + n * 136 + mtb + quad * 4 + 2) = pk2(o[2], o[3]);
        }
    }
    __syncthreads();

    // ---- s3: out rows (rk3 0..63), source m2T, P row rk3+64. 8 units.
    {
        int u = wave;
        int mtb = (u >> 1) * 16;
        int ntb = (u & 1) * 32;
        f32x4 a0 = {0.f,0.f,0.f,0.f}, a1 = a0;
        int ks0 = mtb >> 5;
        const int m = mtb + l16;
#pragma unroll
        for (int t = 0; t < 3; ++t) {
            int k0q = (ks0 + t) * 32 + quad * 8;
            short8 fa;
#pragma unroll
            for (int j = 0; j < 8; ++j) {
                int idx = k0q + j - m;
                int idc = min(max(idx, 0), 64);
                unsigned short pv = ps[(m + 64) * 66 + idc];
                fa[j] = ((unsigned)idx <= 64u) ? (short)pv : (short)0;
            }
            short8 fb0 = *(const short8*)(m2T + (ntb + l16) * 136 + k0q);
            short8 fb1 = *(const short8*)(m2T + (ntb + 16 + l16) * 136 + k0q);
            a0 = __builtin_amdgcn_mfma_f32_16x16x32_bf16(fa, fb0, a0, 0, 0, 0);
            a1 = __builtin_amdgcn_mfma_f32_16x16x32_bf16(fa, fb1, a1, 0, 0, 0);
        }
#pragma unroll
        for (int nt = 0; nt < 2; ++nt) {
            f32x4 a = nt ? a1 : a0;
            int n = ntb + nt * 16 + l16;
#pragma unroll
            for (int r = 0; r < 4; ++r) {
                int gm = i0 + mtb + quad * 4 + r;
                size_t base = (size_t)gm * E_DIM + c0 + n;
                hout[base] = 0.9f * a[r] + 0.1f * v[base];
            }
        }
    }
}

// ---------------------------------------------------------------------------
// oln3 v4 (R15): BK=128 -> 4 k-iterations (was 16). 16 rows x 512 cols per
// block, 128 blocks, 512 threads. Latency-bound diagnosis (R14: VALUBusy 8%,
// MfmaUtil 2% at 44 us): cut the serialized chain 4x. Band build uses all 8
// waves (wave w -> cols w*16, head = (kk+ntb)/64). GEMM: 16 MFMA/wave/iter
// with direct-WoT fb (R14-proven). h4T tail rows [80,96) zeroed once.
// LDS ~47 KB.
// ---------------------------------------------------------------------------
__global__ __launch_bounds__(512)
void oln3(const float* __restrict__ h4, const float* __restrict__ v,
          const float* __restrict__ P, const unsigned short* __restrict__ WoT,
          const float* __restrict__ bo, const float* __restrict__ x,
          const float* __restrict__ g, const float* __restrict__ lb,
          float* __restrict__ out)
{
    __shared__ unsigned short As[16 * 136];     // [m][k 0..127], pad 136
    __shared__ unsigned short h4T[128 * 96];    // [col][row 0..95]
    __shared__ unsigned short ps16[16 * 528];   // [m][head*65+off]
    __shared__ float rsum[8][16], rsq[8][16];
    const int tid = threadIdx.x;
    const int lane = tid & 63, wave = tid >> 6;
    const int quad = lane >> 4, l16 = lane & 15;
    const int m0 = blockIdx.x * 16;

    // zero h4T tail rows [80,96): 128 cols x 16 rows = 2048 u16.
    {
        int col = tid >> 2, r = tid & 3;
#pragma unroll
        for (int t = 0; t < 4; ++t)
            h4T[col * 96 + 80 + r * 4 + t] = 0;
    }
    // stage P rows m0..m0+16 (all heads) once, bf16
    for (int e = tid; e < 16 * 260; e += 512) {
        int mr = e / 260, t = e - mr * 260;
        const float* pr = P + (size_t)(m0 + mr) * PROW;
        *(unsigned*)(ps16 + mr * 528 + t * 2) = pk2(pr[t * 2], pr[t * 2 + 1]);
    }

    f32x4 acc[4];
#pragma unroll
    for (int t = 0; t < 4; ++t) acc[t] = (f32x4){0.f,0.f,0.f,0.f};

    for (int kk = 0; kk < E_DIM; kk += 128) {
        // ---- stage h4 rows [m0-32, m0+48) x 128 cols -> h4T (transposed bf16)
        float4 hv[5];
#pragma unroll
        for (int t = 0; t < 5; ++t) {
            int e = tid + t * 512;                 // e < 2560
            int r = e >> 5, c4 = e & 31;
            int jc = min(max(m0 - 32 + r, 0), S_LEN - 1);
            hv[t] = *(const float4*)(h4 + (size_t)jc * E_DIM + kk + c4 * 4);
        }
        __syncthreads();   // prior iter's h4T/As reads complete
#pragma unroll
        for (int t = 0; t < 5; ++t) {
            int e = tid + t * 512;
            int r = e >> 5, c4 = (e & 31) * 4;
            h4T[(c4 + 0) * 96 + r] = f2bf(hv[t].x);
            h4T[(c4 + 1) * 96 + r] = f2bf(hv[t].y);
            h4T[(c4 + 2) * 96 + r] = f2bf(hv[t].z);
            h4T[(c4 + 3) * 96 + r] = f2bf(hv[t].w);
        }
        __syncthreads();

        // ---- band build (step 5): wave w -> cols [w*16, w*16+16).
        // As[m][c] = 0.9 * (P-band @ h4)[m][c] + 0.1 * v[m0+m][kk+c], bf16.
        {
            const int ntb = wave * 16;
            const int hd = (kk + ntb) >> 6;        // head of these 16 cols
            f32x4 ba = {0.f,0.f,0.f,0.f};
#pragma unroll
            for (int t = 0; t < 3; ++t) {
                int k0q = t * 32 + quad * 8;
                short8 fa;
#pragma unroll
                for (int j = 0; j < 8; ++j) {
                    int idx = k0q + j - l16;       // row m = l16
                    int idc = min(max(idx, 0), 64);
                    unsigned short pv = ps16[l16 * 528 + hd * NOFF + idc];
                    fa[j] = ((unsigned)idx <= 64u) ? (short)pv : (short)0;
                }
                short8 fb = *(const short8*)(h4T + (ntb + l16) * 96 + k0q);
                ba = __builtin_amdgcn_mfma_f32_16x16x32_bf16(fa, fb, ba, 0, 0, 0);
            }
            // C-layout: col = ntb + l16, rows quad*4 + r
#pragma unroll
            for (int r = 0; r < 4; ++r) {
                int m = quad * 4 + r;              // 0..15
                float vv = v[(size_t)(m0 + m) * E_DIM + kk + ntb + l16];
                As[m * 136 + ntb + l16] = f2bf(0.9f * ba[r] + 0.1f * vv);
            }
        }
        __syncthreads();

        // ---- GEMM: 4 n-tiles x 4 k-chunks, fb direct from WoT (L1/L2-hit)
#pragma unroll
        for (int kq = 0; kq < 4; ++kq) {
            short8 fa = *(const short8*)(As + l16 * 136 + kq * 32 + quad * 8);
#pragma unroll
            for (int nt = 0; nt < 4; ++nt) {
                int n = wave * 64 + nt * 16 + l16;
                short8 fb = *(const short8*)(WoT + (size_t)n * E_DIM + kk + kq * 32 + quad * 8);
                acc[nt] = __builtin_amdgcn_mfma_f32_16x16x32_bf16(fa, fb, acc[nt], 0, 0, 0);
            }
        }
    }

    // epilogue: bias + resid, LN (proven R12, 16-row)
    float s[4] = {0.f,0.f,0.f,0.f}, s2[4] = {0.f,0.f,0.f,0.f};
#pragma unroll
    for (int nt = 0; nt < 4; ++nt) {
        int nc = wave * 64 + nt * 16 + l16;
        float bv = bo[nc];
#pragma unroll
        for (int r = 0; r < 4; ++r) {
            int m = m0 + quad * 4 + r;
            float vl = acc[nt][r] + bv + x[(size_t)m * E_DIM + nc];
            acc[nt][r] = vl;
            s[r] += vl; s2[r] += vl * vl;
        }
    }
#pragma unroll
    for (int o = 1; o < 16; o <<= 1) {
#pragma unroll
        for (int r = 0; r < 4; ++r) {
            s[r]  += __shfl_xor(s[r], o, 64);
            s2[r] += __shfl_xor(s2[r], o, 64);
        }
    }
    if (l16 == 0) {
#pragma unroll
        for (int r = 0; r < 4; ++r) {
            rsum[wave][quad * 4 + r] = s[r];
            rsq[wave][quad * 4 + r]  = s2[r];
        }
    }
    __syncthreads();
    float mu[4], rs[4];
#pragma unroll
    for (int r = 0; r < 4; ++r) {
        int rl = quad * 4 + r;
        float tot = 0.f, tot2 = 0.f;
#pragma unroll
        for (int w = 0; w < 8; ++w) { tot += rsum[w][rl]; tot2 += rsq[w][rl]; }
        float m_ = tot * (1.f / 512.f);
        float var = tot2 * (1.f / 512.f) - m_ * m_;
        mu[r] = m_; rs[r] = rsqrtf(var + 1e-12f);
    }
#pragma unroll
    for (int nt = 0; nt < 4; ++nt) {
        int nc = wave * 64 + nt * 16 + l16;
        float gv = g[nc], bbv = lb[nc];
#pragma unroll
        for (int r = 0; r < 4; ++r) {
            int m = m0 + quad * 4 + r;
            out[(size_t)m * E_DIM + nc] = (acc[nt][r] - mu[r]) * rs[r] * gv + bbv;
        }
    }
}

// ---------------------------------------------------------------------------
extern "C" void kernel_launch(void* const* d_in, const int* in_sizes, int n_in,
                              void* d_out, int out_size, void* d_ws, size_t ws_size,
                              hipStream_t stream)
{
    const float* x     = (const float*)d_in[0];
    const float* amask = (const float*)d_in[1];
    const float* Wq = (const float*)d_in[4];
    const float* bq = (const float*)d_in[5];
    const float* Wk = (const float*)d_in[6];
    const float* bk = (const float*)d_in[7];
    const float* Wv = (const float*)d_in[8];
    const float* bv = (const float*)d_in[9];
    const float* Wo = (const float*)d_in[10];
    const float* bo = (const float*)d_in[11];
    const float* lng = (const float*)d_in[12];
    const float* lnb = (const float*)d_in[13];
    float* out = (float*)d_out;

    float* ws = (float*)d_ws;
    float* q  = ws;
    float* k  = ws + (size_t)NE;
    float* v  = ws + (size_t)2 * NE;
    float* P  = ws + (size_t)3 * NE;
    float* hA = ws + (size_t)3 * NE + PN;
    float* hB = hA + (size_t)NE;
    unsigned short* WoT = (unsigned short*)(hB + (size_t)NE);   // 512x512 bf16

    qkv_gemm<<<dim3(8, 32, 4), 256, 0, stream>>>(x, Wq, bq, Wk, bk, Wv, bv,
                                                 Wo, WoT, q, k, v);

    scores_d1<<<dim3(64, 8), 256, 0, stream>>>(q, k, v, amask, P, hA);   // P + step 1

    diffuse3m<<<dim3(32, 8), 512, 0, stream>>>(hA, v, P, hB);            // steps 2-4

    oln3<<<128, 512, 0, stream>>>(hB, v, P, WoT, bo, x, lng, lnb, out);  // step 5 + GEMM + LN
}

// Round 16
// 172.191 us; speedup vs baseline: 1.0570x; 1.0570x over previous
//
#include <hip/hip_runtime.h>
#include <math.h>

#define S_LEN 2048
#define E_DIM 512
#define NE (S_LEN * E_DIM)
#define H_NUM 8
#define WH 32
#define NOFF 65
#define PROW (H_NUM * NOFF) /* 520 */
#define PN (S_LEN * PROW)

typedef float f32x4 __attribute__((ext_vector_type(4)));
typedef short short8 __attribute__((ext_vector_type(8)));

__device__ __forceinline__ unsigned short f2bf(float f) {
    union { float f; unsigned u; } cv; cv.f = f;
    unsigned u = cv.u;
    u += 0x7fffu + ((u >> 16) & 1u);   // RNE
    return (unsigned short)(u >> 16);
}
__device__ __forceinline__ unsigned pk2(float x, float y) {
    return (unsigned)f2bf(x) | ((unsigned)f2bf(y) << 16);
}

// ---------------------------------------------------------------------------
// qkv (proven R3/R8): C = (x@W + bias)*scale, in-kernel bf16 cast, 64x64 tiles.
// ---------------------------------------------------------------------------
__device__ __forceinline__ void mfma_gemm_f32(
    const float* __restrict__ A, const float* __restrict__ W,
    const float* __restrict__ bias, float* __restrict__ C,
    float scale, int m0, int n0)
{
    __shared__ unsigned short As[64 * 40];
    __shared__ unsigned short Bs[64 * 40];
    const int tid = threadIdx.x;
    const int lane = tid & 63, wave = tid >> 6;
    const int quad = lane >> 4, l16 = lane & 15;
    const int wr = (wave >> 1) * 32, wc = (wave & 1) * 32;
    const int ar = tid >> 2, ac = (tid & 3) * 8;
    const int bn = tid & 63, bk0 = (tid >> 6) * 8;

    f32x4 acc00 = {0.f,0.f,0.f,0.f}, acc01 = acc00, acc10 = acc00, acc11 = acc00;

    for (int kk = 0; kk < E_DIM; kk += 32) {
        float4 a0 = *(const float4*)(A + (size_t)(m0 + ar) * E_DIM + kk + ac);
        float4 a1 = *(const float4*)(A + (size_t)(m0 + ar) * E_DIM + kk + ac + 4);
        float b[8];
#pragma unroll
        for (int j = 0; j < 8; ++j)
            b[j] = W[(size_t)(kk + bk0 + j) * E_DIM + n0 + bn];
        __syncthreads();
        uint4 ap; ap.x = pk2(a0.x, a0.y); ap.y = pk2(a0.z, a0.w);
        ap.z = pk2(a1.x, a1.y); ap.w = pk2(a1.z, a1.w);
        *(uint4*)(As + ar * 40 + ac) = ap;
        uint4 bp; bp.x = pk2(b[0], b[1]); bp.y = pk2(b[2], b[3]);
        bp.z = pk2(b[4], b[5]); bp.w = pk2(b[6], b[7]);
        *(uint4*)(Bs + bn * 40 + bk0) = bp;
        __syncthreads();
        short8 fa0 = *(const short8*)(As + (wr + l16) * 40 + quad * 8);
        short8 fa1 = *(const short8*)(As + (wr + 16 + l16) * 40 + quad * 8);
        short8 fb0 = *(const short8*)(Bs + (wc + l16) * 40 + quad * 8);
        short8 fb1 = *(const short8*)(Bs + (wc + 16 + l16) * 40 + quad * 8);
        acc00 = __builtin_amdgcn_mfma_f32_16x16x32_bf16(fa0, fb0, acc00, 0, 0, 0);
        acc01 = __builtin_amdgcn_mfma_f32_16x16x32_bf16(fa0, fb1, acc01, 0, 0, 0);
        acc10 = __builtin_amdgcn_mfma_f32_16x16x32_bf16(fa1, fb0, acc10, 0, 0, 0);
        acc11 = __builtin_amdgcn_mfma_f32_16x16x32_bf16(fa1, fb1, acc11, 0, 0, 0);
    }

#pragma unroll
    for (int mi = 0; mi < 2; ++mi) {
#pragma unroll
        for (int ni = 0; ni < 2; ++ni) {
            f32x4 a = (mi == 0) ? ((ni == 0) ? acc00 : acc01)
                                : ((ni == 0) ? acc10 : acc11);
            int n = n0 + wc + ni * 16 + l16;
            float bval = bias[n];
#pragma unroll
            for (int r = 0; r < 4; ++r) {
                int m = m0 + wr + mi * 16 + quad * 4 + r;
                C[(size_t)m * E_DIM + n] = (a[r] + bval) * scale;
            }
        }
    }
}

__global__ __launch_bounds__(256)
void qkv_gemm(const float* __restrict__ x,
              const float* __restrict__ Wq, const float* __restrict__ bq,
              const float* __restrict__ Wk, const float* __restrict__ bk,
              const float* __restrict__ Wv, const float* __restrict__ bv,
              float* __restrict__ q, float* __restrict__ k, float* __restrict__ v)
{
    const float* W; const float* b; float* o; float sc;
    if (blockIdx.z == 0)      { W = Wq; b = bq; o = q; sc = 0.125f; }
    else if (blockIdx.z == 1) { W = Wk; b = bk; o = k; sc = 1.0f; }
    else                      { W = Wv; b = bv; o = v; sc = 1.0f; }
    mfma_gemm_f32(x, W, b, o, sc, blockIdx.y * 64, blockIdx.x * 64);
}

// ---------------------------------------------------------------------------
// scores_d1 (proven R8): scores + edge-softmax + diffusion step 1, fused.
// ---------------------------------------------------------------------------
#define SDN 32
__global__ __launch_bounds__(256)
void scores_d1(const float* __restrict__ q, const float* __restrict__ k,
               const float* __restrict__ v, const float* __restrict__ amask,
               float* __restrict__ P, float* __restrict__ hA)
{
    const int i0 = blockIdx.x * SDN;
    const int h  = blockIdx.y;
    const int tid = threadIdx.x;
    __shared__ float ks[96 * 68];      // k rows [i0-32,i0+64); later v rows
    __shared__ float am[96];
    __shared__ float sc[SDN * 66];
    __shared__ float smx[SDN], sidn[SDN];
    __shared__ float ps[SDN * NOFF];

    for (int e = tid; e < 96 * 16; e += 256) {
        int lr = e >> 4, c4 = e & 15;
        int j = i0 - WH + lr;
        int jc = min(max(j, 0), S_LEN - 1);
        *(float4*)(ks + lr * 68 + c4 * 4) =
            *(const float4*)(k + (size_t)jc * E_DIM + h * 64 + c4 * 4);
    }
    if (tid < 96) {
        int j = i0 - WH + tid;
        am[tid] = (j >= 0 && j < S_LEN) ? amask[j] : -1.0f;
    }

    const int dst = tid >> 3;
    const int og  = tid & 7;
    float4 qreg[16];
    {
        const float4* qrow = (const float4*)(q + (size_t)(i0 + dst) * E_DIM + h * 64);
#pragma unroll
        for (int t = 0; t < 16; ++t) qreg[t] = qrow[t];
    }
    __syncthreads();

    for (int off = og; off < NOFF; off += 8) {
        int j = i0 + dst + off - WH;
        float s;
        if (j < 0 || j >= S_LEN) {
            s = -INFINITY;
        } else {
            int lr = dst + off;
            const float4* kr = (const float4*)(ks + lr * 68);
            float acc = 0.f;
#pragma unroll
            for (int t = 0; t < 16; ++t) {
                float4 a = qreg[t], bb = kr[t];
                acc += a.x * bb.x + a.y * bb.y + a.z * bb.z + a.w * bb.w;
            }
            s = (am[lr] >= 0.f) ? acc : -1e9f;
        }
        sc[dst * 66 + off] = s;
    }
    __syncthreads();   // sc done; ks no longer read as k

    for (int e = tid; e < 96 * 16; e += 256) {
        int lr = e >> 4, c4 = e & 15;
        int j = i0 - WH + lr;
        int jc = min(max(j, 0), S_LEN - 1);
        *(float4*)(ks + lr * 68 + c4 * 4) =
            *(const float4*)(v + (size_t)jc * E_DIM + h * 64 + c4 * 4);
    }
    if (tid < SDN) {
        float mx = -INFINITY;
        for (int o = 0; o < NOFF; ++o) mx = fmaxf(mx, sc[tid * 66 + o]);
        float dn = 0.f;
        for (int o = 0; o < NOFF; ++o) dn += expf(sc[tid * 66 + o] - mx);
        smx[tid] = mx; sidn[tid] = 1.f / dn;
    }
    __syncthreads();

    for (int e = tid; e < SDN * NOFF; e += 256) {
        int d = e / NOFF, off = e - d * NOFF;
        float pv = expf(sc[d * 66 + off] - smx[d]) * sidn[d];
        P[(size_t)(i0 + d) * PROW + h * NOFF + off] = pv;
        ps[e] = pv;
    }
    __syncthreads();

    {
        const int ci = tid & 15;
        const int ob = (tid >> 4) * 2;
        float4 a0 = {0,0,0,0}, a1 = a0;
        for (int lr = ob; lr < ob + 66; ++lr) {
            float4 hval = *(const float4*)(ks + lr * 68 + ci * 4);
            int o0 = lr - ob;
            if (o0 <= 64) {
                float p = ps[ob * NOFF + o0];
                a0.x += p * hval.x; a0.y += p * hval.y; a0.z += p * hval.z; a0.w += p * hval.w;
            }
            int o1 = o0 - 1;
            if ((unsigned)o1 <= 64u) {
                float p = ps[(ob + 1) * NOFF + o1];
                a1.x += p * hval.x; a1.y += p * hval.y; a1.z += p * hval.z; a1.w += p * hval.w;
            }
        }
#pragma unroll
        for (int r = 0; r < 2; ++r) {
            float4 a = r ? a1 : a0;
            float4 vv = *(const float4*)(ks + (WH + ob + r) * 68 + ci * 4);
            float4 o;
            o.x = 0.9f * a.x + 0.1f * vv.x;
            o.y = 0.9f * a.y + 0.1f * vv.y;
            o.z = 0.9f * a.z + 0.1f * vv.z;
            o.w = 0.9f * a.w + 0.1f * vv.w;
            *(float4*)(hA + (size_t)(i0 + ob + r) * E_DIM + h * 64 + ci * 4) = o;
        }
    }
}

// ---------------------------------------------------------------------------
// diffuse3m (proven R12): THREE diffusion steps via banded MFMA.
// block = 64 out rows x 64 cols (one head), 512 thr (8 waves). grid (32,8).
// ---------------------------------------------------------------------------
__global__ __launch_bounds__(512)
void diffuse3m(const float* __restrict__ hin, const float* __restrict__ v,
               const float* __restrict__ P, float* __restrict__ hout)
{
    __shared__ unsigned short inT[64 * 264];  // [col][in-row 0..255]; later m2T
    __shared__ unsigned short m1T[64 * 200];  // [col][mid1-row 0..191]
    __shared__ unsigned short ps[192 * 66];   // [row rk1][off 0..64] bf16
    unsigned short* m2T = inT;                // [col][mid2-row 0..127] stride 136
    const int i0 = blockIdx.x * 64;
    const int h  = blockIdx.y;
    const int c0 = h * 64;
    const int tid  = threadIdx.x;
    const int lane = tid & 63, wave = tid >> 6;
    const int quad = lane >> 4, l16 = lane & 15;

    for (int e = tid; e < 128 * 16; e += 512) {
        int rp = (e >> 4) * 2, c4 = (e & 15) * 4;
        int ja = min(max(i0 - 96 + rp,     0), S_LEN - 1);
        int jb = min(max(i0 - 96 + rp + 1, 0), S_LEN - 1);
        float4 ha = *(const float4*)(hin + (size_t)ja * E_DIM + c0 + c4);
        float4 hb = *(const float4*)(hin + (size_t)jb * E_DIM + c0 + c4);
        *(unsigned*)(inT + (c4 + 0) * 264 + rp) = pk2(ha.x, hb.x);
        *(unsigned*)(inT + (c4 + 1) * 264 + rp) = pk2(ha.y, hb.y);
        *(unsigned*)(inT + (c4 + 2) * 264 + rp) = pk2(ha.z, hb.z);
        *(unsigned*)(inT + (c4 + 3) * 264 + rp) = pk2(ha.w, hb.w);
    }
    for (int e = tid; e < 192 * 33; e += 512) {
        int mr = e / 33, t = e - mr * 33;
        int jc = min(max(i0 - 64 + mr, 0), S_LEN - 1);
        const float* pr = P + (size_t)jc * PROW + h * NOFF;
        if (t < 32)
            *(unsigned*)(ps + mr * 66 + t * 2) = pk2(pr[t * 2], pr[t * 2 + 1]);
        else
            ps[mr * 66 + 64] = f2bf(pr[64]);
    }
    __syncthreads();

    // ---- s1: mid1 rows (rk1 0..191). 24 units (12 m-tiles x 2 n-halves).
#pragma unroll
    for (int uu = 0; uu < 3; ++uu) {
        int u = wave + uu * 8;
        int mtb = (u >> 1) * 16;
        int ntb = (u & 1) * 32;
        f32x4 a0 = {0.f,0.f,0.f,0.f}, a1 = a0;
        int ks0 = mtb >> 5;
        const int m = mtb + l16;
#pragma unroll
        for (int t = 0; t < 3; ++t) {
            int k0q = (ks0 + t) * 32 + quad * 8;
            short8 fa;
#pragma unroll
            for (int j = 0; j < 8; ++j) {
                int idx = k0q + j - m;
                int idc = min(max(idx, 0), 64);
                unsigned short pv = ps[m * 66 + idc];
                fa[j] = ((unsigned)idx <= 64u) ? (short)pv : (short)0;
            }
            short8 fb0 = *(const short8*)(inT + (ntb + l16) * 264 + k0q);
            short8 fb1 = *(const short8*)(inT + (ntb + 16 + l16) * 264 + k0q);
            a0 = __builtin_amdgcn_mfma_f32_16x16x32_bf16(fa, fb0, a0, 0, 0, 0);
            a1 = __builtin_amdgcn_mfma_f32_16x16x32_bf16(fa, fb1, a1, 0, 0, 0);
        }
#pragma unroll
        for (int nt = 0; nt < 2; ++nt) {
            f32x4 a = nt ? a1 : a0;
            int n = ntb + nt * 16 + l16;
            float o[4];
#pragma unroll
            for (int r = 0; r < 4; ++r) {
                int gm = min(max(i0 - 64 + mtb + quad * 4 + r, 0), S_LEN - 1);
                o[r] = 0.9f * a[r] + 0.1f * v[(size_t)gm * E_DIM + c0 + n];
            }
            *(unsigned*)(m1T + n * 200 + mtb + quad * 4)     = pk2(o[0], o[1]);
            *(unsigned*)(m1T + n * 200 + mtb + quad * 4 + 2) = pk2(o[2], o[3]);
        }
    }
    __syncthreads();

    // ---- s2: mid2 rows (rk2 0..127), source m1T, P row rk2+32. 16 units.
    // Writes m2T which overlays inT (inT dead after s1).
#pragma unroll
    for (int uu = 0; uu < 2; ++uu) {
        int u = wave + uu * 8;
        int mtb = (u >> 1) * 16;
        int ntb = (u & 1) * 32;
        f32x4 a0 = {0.f,0.f,0.f,0.f}, a1 = a0;
        int ks0 = mtb >> 5;
        const int m = mtb + l16;
#pragma unroll
        for (int t = 0; t < 3; ++t) {
            int k0q = (ks0 + t) * 32 + quad * 8;
            short8 fa;
#pragma unroll
            for (int j = 0; j < 8; ++j) {
                int idx = k0q + j - m;
                int idc = min(max(idx, 0), 64);
                unsigned short pv = ps[(m + 32) * 66 + idc];
                fa[j] = ((unsigned)idx <= 64u) ? (short)pv : (short)0;
            }
            short8 fb0 = *(const short8*)(m1T + (ntb + l16) * 200 + k0q);
            short8 fb1 = *(const short8*)(m1T + (ntb + 16 + l16) * 200 + k0q);
            a0 = __builtin_amdgcn_mfma_f32_16x16x32_bf16(fa, fb0, a0, 0, 0, 0);
            a1 = __builtin_amdgcn_mfma_f32_16x16x32_bf16(fa, fb1, a1, 0, 0, 0);
        }
        __syncthreads();   // uniform across waves; orders m2T writes vs any
                           // straggling inT reads (defensive -- inT is dead)
#pragma unroll
        for (int nt = 0; nt < 2; ++nt) {
            f32x4 a = nt ? a1 : a0;
            int n = ntb + nt * 16 + l16;
            float o[4];
#pragma unroll
            for (int r = 0; r < 4; ++r) {
                int gm = min(max(i0 - 32 + mtb + quad * 4 + r, 0), S_LEN - 1);
                o[r] = 0.9f * a[r] + 0.1f * v[(size_t)gm * E_DIM + c0 + n];
            }
            *(unsigned*)(m2T + n * 136 + mtb + quad * 4)     = pk2(o[0], o[1]);
            *(unsigned*)(m2T + n * 136 + mtb + quad * 4 + 2) = pk2(o[2], o[3]);
        }
    }
    __syncthreads();

    // ---- s3: out rows (rk3 0..63), source m2T, P row rk3+64. 8 units.
    {
        int u = wave;
        int mtb = (u >> 1) * 16;
        int ntb = (u & 1) * 32;
        f32x4 a0 = {0.f,0.f,0.f,0.f}, a1 = a0;
        int ks0 = mtb >> 5;
        const int m = mtb + l16;
#pragma unroll
        for (int t = 0; t < 3; ++t) {
            int k0q = (ks0 + t) * 32 + quad * 8;
            short8 fa;
#pragma unroll
            for (int j = 0; j < 8; ++j) {
                int idx = k0q + j - m;
                int idc = min(max(idx, 0), 64);
                unsigned short pv = ps[(m + 64) * 66 + idc];
                fa[j] = ((unsigned)idx <= 64u) ? (short)pv : (short)0;
            }
            short8 fb0 = *(const short8*)(m2T + (ntb + l16) * 136 + k0q);
            short8 fb1 = *(const short8*)(m2T + (ntb + 16 + l16) * 136 + k0q);
            a0 = __builtin_amdgcn_mfma_f32_16x16x32_bf16(fa, fb0, a0, 0, 0, 0);
            a1 = __builtin_amdgcn_mfma_f32_16x16x32_bf16(fa, fb1, a1, 0, 0, 0);
        }
#pragma unroll
        for (int nt = 0; nt < 2; ++nt) {
            f32x4 a = nt ? a1 : a0;
            int n = ntb + nt * 16 + l16;
#pragma unroll
            for (int r = 0; r < 4; ++r) {
                int gm = i0 + mtb + quad * 4 + r;   // always in range
                size_t base = (size_t)gm * E_DIM + c0 + n;
                hout[base] = 0.9f * a[r] + 0.1f * v[base];
            }
        }
    }
}

// ---------------------------------------------------------------------------
// oln3 (proven R12): diffusion step 5 (banded MFMA, waves 0-1) + h@Wo + bo +
// x + LayerNorm. Block = 16 rows x 512 cols, 512 threads, 128 blocks.
// h4T tail rows [80,96) zeroed once (R12 NaN fix).
// ---------------------------------------------------------------------------
__global__ __launch_bounds__(512)
void oln3(const float* __restrict__ h4, const float* __restrict__ v,
          const float* __restrict__ P, const float* __restrict__ Wo,
          const float* __restrict__ bo, const float* __restrict__ x,
          const float* __restrict__ g, const float* __restrict__ lb,
          float* __restrict__ out)
{
    __shared__ unsigned short As[16 * 40];      // 1280 B
    __shared__ unsigned short Bs[512 * 40];     // 40960 B
    __shared__ unsigned short h4T[32 * 96];     // 6144 B  [col][row 0..95]
    __shared__ unsigned short ps16[16 * 528];   // 16896 B [m][head*65+off]
    __shared__ float rsum[8][16], rsq[8][16];   // 1024 B
    const int tid = threadIdx.x;
    const int lane = tid & 63, wave = tid >> 6;
    const int quad = lane >> 4, l16 = lane & 15;
    const int m0 = blockIdx.x * 16;
    const int n = tid;

    // zero un-staged h4T tail rows [80,96) (32 cols x 16 rows = 512 u16).
    {
        int col = tid >> 4, r = tid & 15;
        h4T[col * 96 + 80 + r] = 0;
    }
    // stage P rows m0..m0+16 (all heads) once, bf16
    for (int e = tid; e < 16 * 260; e += 512) {
        int mr = e / 260, t = e - mr * 260;
        const float* pr = P + (size_t)(m0 + mr) * PROW;
        *(unsigned*)(ps16 + mr * 528 + t * 2) = pk2(pr[t * 2], pr[t * 2 + 1]);
    }

    f32x4 acc[4];
#pragma unroll
    for (int t = 0; t < 4; ++t) acc[t] = (f32x4){0.f,0.f,0.f,0.f};

    for (int kk = 0; kk < E_DIM; kk += 32) {
        const int hd = kk >> 6;
        // global loads pre-barrier
        float4 hv0, hv1;
        {
            int r = tid >> 3, c4 = (tid & 7) * 4;
            int jc = min(max(m0 - 32 + r, 0), S_LEN - 1);
            hv0 = *(const float4*)(h4 + (size_t)jc * E_DIM + kk + c4);
        }
        if (tid < 128) {
            int e = tid + 512;
            int r = e >> 3, c4 = (e & 7) * 4;
            int jc = min(max(m0 - 32 + r, 0), S_LEN - 1);
            hv1 = *(const float4*)(h4 + (size_t)jc * E_DIM + kk + c4);
        }
        float bcol[32];
#pragma unroll
        for (int j = 0; j < 32; ++j)
            bcol[j] = Wo[(size_t)(kk + j) * E_DIM + n];
        __syncthreads();   // prior iter's As/Bs/h4T reads complete
        {
            int r = tid >> 3, c4 = (tid & 7) * 4;
            h4T[(c4 + 0) * 96 + r] = f2bf(hv0.x);
            h4T[(c4 + 1) * 96 + r] = f2bf(hv0.y);
            h4T[(c4 + 2) * 96 + r] = f2bf(hv0.z);
            h4T[(c4 + 3) * 96 + r] = f2bf(hv0.w);
        }
        if (tid < 128) {
            int e = tid + 512;
            int r = e >> 3, c4 = (e & 7) * 4;
            h4T[(c4 + 0) * 96 + r] = f2bf(hv1.x);
            h4T[(c4 + 1) * 96 + r] = f2bf(hv1.y);
            h4T[(c4 + 2) * 96 + r] = f2bf(hv1.z);
            h4T[(c4 + 3) * 96 + r] = f2bf(hv1.w);
        }
#pragma unroll
        for (int t = 0; t < 4; ++t) {
            uint4 bp;
            bp.x = pk2(bcol[t*8+0], bcol[t*8+1]); bp.y = pk2(bcol[t*8+2], bcol[t*8+3]);
            bp.z = pk2(bcol[t*8+4], bcol[t*8+5]); bp.w = pk2(bcol[t*8+6], bcol[t*8+7]);
            *(uint4*)(Bs + n * 40 + t * 8) = bp;
        }
        __syncthreads();

        // band build (step 5): waves 0-1 produce As[16 m][32 c] = 0.9*P@h4 + 0.1*v
        if (wave < 2) {
            const int ntb = wave * 16;
            f32x4 ba = {0.f,0.f,0.f,0.f};
#pragma unroll
            for (int t = 0; t < 3; ++t) {
                int k0q = t * 32 + quad * 8;
                short8 fa;
#pragma unroll
                for (int j = 0; j < 8; ++j) {
                    int idx = k0q + j - l16;          // row m = l16
                    int idc = min(max(idx, 0), 64);
                    unsigned short pv = ps16[l16 * 528 + hd * NOFF + idc];
                    fa[j] = ((unsigned)idx <= 64u) ? (short)pv : (short)0;
                }
                short8 fb = *(const short8*)(h4T + (ntb + l16) * 96 + k0q);
                ba = __builtin_amdgcn_mfma_f32_16x16x32_bf16(fa, fb, ba, 0, 0, 0);
            }
#pragma unroll
            for (int r = 0; r < 4; ++r) {
                int m = quad * 4 + r;
                float vv = v[(size_t)(m0 + m) * E_DIM + kk + ntb + l16];
                As[m * 40 + ntb + l16] = f2bf(0.9f * ba[r] + 0.1f * vv);
            }
        }
        __syncthreads();

        short8 fa = *(const short8*)(As + l16 * 40 + quad * 8);
#pragma unroll
        for (int nt = 0; nt < 4; ++nt) {
            short8 fb = *(const short8*)(Bs + (wave * 64 + nt * 16 + l16) * 40 + quad * 8);
            acc[nt] = __builtin_amdgcn_mfma_f32_16x16x32_bf16(fa, fb, acc[nt], 0, 0, 0);
        }
    }

    // epilogue: bias + resid, LN (proven R4/R6/R8)
    float s[4] = {0.f,0.f,0.f,0.f}, s2[4] = {0.f,0.f,0.f,0.f};
#pragma unroll
    for (int nt = 0; nt < 4; ++nt) {
        int nc = wave * 64 + nt * 16 + l16;
        float bv = bo[nc];
#pragma unroll
        for (int r = 0; r < 4; ++r) {
            int m = m0 + quad * 4 + r;
            float vl = acc[nt][r] + bv + x[(size_t)m * E_DIM + nc];
            acc[nt][r] = vl;
            s[r] += vl; s2[r] += vl * vl;
        }
    }
#pragma unroll
    for (int o = 1; o < 16; o <<= 1) {
#pragma unroll
        for (int r = 0; r < 4; ++r) {
            s[r]  += __shfl_xor(s[r], o, 64);
            s2[r] += __shfl_xor(s2[r], o, 64);
        }
    }
    if (l16 == 0) {
#pragma unroll
        for (int r = 0; r < 4; ++r) {
            rsum[wave][quad * 4 + r] = s[r];
            rsq[wave][quad * 4 + r]  = s2[r];
        }
    }
    __syncthreads();
    float mu[4], rs[4];
#pragma unroll
    for (int r = 0; r < 4; ++r) {
        int rl = quad * 4 + r;
        float tot = 0.f, tot2 = 0.f;
#pragma unroll
        for (int w = 0; w < 8; ++w) { tot += rsum[w][rl]; tot2 += rsq[w][rl]; }
        float m_ = tot * (1.f / 512.f);
        float var = tot2 * (1.f / 512.f) - m_ * m_;
        mu[r] = m_; rs[r] = rsqrtf(var + 1e-12f);
    }
#pragma unroll
    for (int nt = 0; nt < 4; ++nt) {
        int nc = wave * 64 + nt * 16 + l16;
        float gv = g[nc], bbv = lb[nc];
#pragma unroll
        for (int r = 0; r < 4; ++r) {
            int m = m0 + quad * 4 + r;
            out[(size_t)m * E_DIM + nc] = (acc[nt][r] - mu[r]) * rs[r] * gv + bbv;
        }
    }
}

// ---------------------------------------------------------------------------
extern "C" void kernel_launch(void* const* d_in, const int* in_sizes, int n_in,
                              void* d_out, int out_size, void* d_ws, size_t ws_size,
                              hipStream_t stream)
{
    const float* x     = (const float*)d_in[0];
    const float* amask = (const float*)d_in[1];
    const float* Wq = (const float*)d_in[4];
    const float* bq = (const float*)d_in[5];
    const float* Wk = (const float*)d_in[6];
    const float* bk = (const float*)d_in[7];
    const float* Wv = (const float*)d_in[8];
    const float* bv = (const float*)d_in[9];
    const float* Wo = (const float*)d_in[10];
    const float* bo = (const float*)d_in[11];
    const float* lng = (const float*)d_in[12];
    const float* lnb = (const float*)d_in[13];
    float* out = (float*)d_out;

    float* ws = (float*)d_ws;
    float* q  = ws;
    float* k  = ws + (size_t)NE;
    float* v  = ws + (size_t)2 * NE;
    float* P  = ws + (size_t)3 * NE;
    float* hA = ws + (size_t)3 * NE + PN;
    float* hB = hA + (size_t)NE;

    qkv_gemm<<<dim3(8, 32, 3), 256, 0, stream>>>(x, Wq, bq, Wk, bk, Wv, bv, q, k, v);

    scores_d1<<<dim3(64, 8), 256, 0, stream>>>(q, k, v, amask, P, hA);   // P + step 1

    diffuse3m<<<dim3(32, 8), 512, 0, stream>>>(hA, v, P, hB);            // steps 2-4

    oln3<<<128, 512, 0, stream>>>(hB, v, P, Wo, bo, x, lng, lnb, out);   // step 5 + GEMM + LN
}